// Round 5
// baseline (156.773 us; speedup 1.0000x reference)
//
#include <hip/hip_runtime.h>
#include <hip/hip_bf16.h>
#include <stdint.h>

// Problem constants (B=4, L=4096, D=1024, K=3)
#define B_SZ   4
#define L_SEQ  4096
#define D_DIM  1024
#define M_TOT  (B_SZ * L_SEQ)   // 16384

typedef __bf16 bf16;
typedef __attribute__((ext_vector_type(8))) __bf16 bf16x8;
typedef __attribute__((ext_vector_type(4))) float   f32x4;

#define GLOAD_LDS16(g, l)                                                     \
  __builtin_amdgcn_global_load_lds(                                           \
      (const __attribute__((address_space(1))) void*)(g),                     \
      (__attribute__((address_space(3))) void*)(l), 16, 0, 0)

// ---------------------------------------------------------------------------
// Kernel 1 (VERBATIM, proven): causal depthwise conv (K=3) + bf16 cast.
// Blocks >= M_TOT/16 do w_pw fp32->bf16 (bf16 B keeps the GEMM's B operand
// at 2MB so it stays XCD-L2-resident).
// ---------------------------------------------------------------------------
__global__ __launch_bounds__(256) void dw_bf16_kernel(
    const float* __restrict__ x, const float* __restrict__ w_dw,
    const float* __restrict__ b_dw, bf16* __restrict__ y,
    const float* __restrict__ w_pw, bf16* __restrict__ wpwb) {
  const int t = threadIdx.x;
  if (blockIdx.x >= B_SZ * (L_SEQ / 16)) {
    int i = ((blockIdx.x - B_SZ * (L_SEQ / 16)) * 256 + t) * 8;
    float4 a = *(const float4*)(w_pw + i);
    float4 b = *(const float4*)(w_pw + i + 4);
    union { bf16 h[8]; int4 v; } r;
    r.h[0] = (bf16)a.x; r.h[1] = (bf16)a.y; r.h[2] = (bf16)a.z; r.h[3] = (bf16)a.w;
    r.h[4] = (bf16)b.x; r.h[5] = (bf16)b.y; r.h[6] = (bf16)b.z; r.h[7] = (bf16)b.w;
    *(int4*)(wpwb + i) = r.v;
    return;
  }
  const int b  = blockIdx.x >> 8;     // / (L_SEQ/16 = 256)
  const int l0 = (blockIdx.x & 255) * 16;
  const int d0 = t * 4;
  const float* xb = x + (size_t)b * L_SEQ * D_DIM + d0;
  bf16*        yb = y + (size_t)b * L_SEQ * D_DIM + d0;

  float4 xr[18];
  const float4 zero = make_float4(0.f, 0.f, 0.f, 0.f);
  xr[0] = (l0 >= 2) ? *(const float4*)(xb + (size_t)(l0 - 2) * D_DIM) : zero;
  xr[1] = (l0 >= 1) ? *(const float4*)(xb + (size_t)(l0 - 1) * D_DIM) : zero;
#pragma unroll
  for (int j = 0; j < 16; ++j)
    xr[j + 2] = *(const float4*)(xb + (size_t)(l0 + j) * D_DIM);

  const float* wp = w_dw + d0 * 3;
  float4 wa = *(const float4*)(wp);      // d0:k0,k1,k2  d1:k0
  float4 wb = *(const float4*)(wp + 4);  // d1:k1,k2     d2:k0,k1
  float4 wc = *(const float4*)(wp + 8);  // d2:k2        d3:k0,k1,k2
  float4 bv = *(const float4*)(b_dw + d0);

#pragma unroll
  for (int j = 0; j < 16; ++j) {
    float4 x2 = xr[j], x1 = xr[j + 1], x0 = xr[j + 2];
    float a0 = fmaf(x2.x, wa.x, fmaf(x1.x, wa.y, fmaf(x0.x, wa.z, bv.x)));
    float a1 = fmaf(x2.y, wa.w, fmaf(x1.y, wb.x, fmaf(x0.y, wb.y, bv.y)));
    float a2 = fmaf(x2.z, wb.z, fmaf(x1.z, wb.w, fmaf(x0.z, wc.x, bv.z)));
    float a3 = fmaf(x2.w, wc.y, fmaf(x1.w, wc.z, fmaf(x0.w, wc.w, bv.w)));
    union { bf16 h[4]; int2 v; } o;
    o.h[0] = (bf16)a0; o.h[1] = (bf16)a1; o.h[2] = (bf16)a2; o.h[3] = (bf16)a3;
    *(int2*)(yb + (size_t)(l0 + j) * D_DIM) = o.v;
  }
}

// ---------------------------------------------------------------------------
// Kernel 2: 256x256 8-wave GEMM, K-slice ring-4 + FINE 2-cluster phases.
//   out[m][n] = sum_k y[m][k] * wpwb[n][k] + b_pw[n]
// M=16384, N=1024, K=1024 -> 32 K-slices of 32.
//
// Ring/wait calculus IDENTICAL to the passed round-4 kernel (slot s&3,
// stage slice s+3 during slice s, VM(8) at slice start proves slice s with
// s+1/s+2's 8 loads in flight; tail 4->0). The delta is intra-slice order
// (m201's lever, m196): each slice is split into two 16-MFMA clusters with
// a barrier pair, ds_reads issued BEFORE the pre-cluster barrier (latency
// hides under rendezvous + prior cluster's matrix-pipe drain), and the 4
// staging DMAs split 2+2 across the clusters. No lifetime change => no new
// race surface; the extra barrier only tightens ordering.
//
// Slice body:
//   VM(8); SB;                       // slot s proven + globally visible
//   readB(4 b128) + readA0(4 b128); stage A-halves of s+3; SB;
//   setprio1; 16 MFMA (i0-3 x j0-3); setprio0;
//   readA1(4 b128); stage B-halves of s+3; SB;
//   setprio1; 16 MFMA (i4-7 x j0-3); setprio0;
//
// Swizzle (proven r0/r2/r4): read c' = q ^ ((row>>1)&3) at 64B pitch; write
// side pre-swizzles the GLOBAL source; LDS dest of gload_lds stays linear.
// GRID (m=x fastest): XCD = bx%8 -> A panel fetched ~once (FETCH 24.6MB).
// ---------------------------------------------------------------------------
#define EP_ROWP 68
#define SB  __builtin_amdgcn_s_barrier()
#define SCB __builtin_amdgcn_sched_barrier(0)
#define VM(N) asm volatile("s_waitcnt vmcnt(" #N ")" ::: "memory")

__global__ __launch_bounds__(512, 2) void gemm256_kernel(
    const bf16* __restrict__ A,   // M x K row-major (y, bf16)
    const bf16* __restrict__ Bm,  // N x K row-major (wpwb, bf16)
    const float* __restrict__ bias, float* __restrict__ C) {
  __shared__ __align__(16) char smem[131072];
  // A-slots: 0,16K,32K,48K ; B-slots: 64K,80K,96K,112K

  const int t    = threadIdx.x;
  const int m0   = blockIdx.x * 256;  // grid.x = 64 (m) — fastest
  const int n0   = blockIdx.y * 256;  // grid.y = 4 (n)
  const int lane = t & 63;
  const int wv   = t >> 6;
  const int wmh  = wv >> 2;   // 0..1: m-half (128 rows)
  const int wn   = wv & 3;    // 0..3: n-quarter (64 cols)
  const int lrow = lane & 15;
  const int q    = lane >> 4;

  // frag read bases within a slot: row*64 + c'*16, c' = q ^ ((row>>1)&3)
  const unsigned cx    = (((unsigned)q ^ (((unsigned)lrow >> 1) & 3)) << 4);
  const unsigned baseA = (unsigned)((wmh * 128 + lrow) * 64) + cx;
  const unsigned baseB = (unsigned)((wn * 64 + lrow) * 64) + cx;

  // stage source (pre-swizzled global): granule g = r*512+t ->
  // row = r*128 + (t>>2), chunk gc = (t&3) ^ ((row>>1)&3)  (r-invariant)
  const int grow = t >> 2;                          // + r*128
  const int gc   = (t & 3) ^ ((grow >> 1) & 3);
  const bf16* aSrc = A  + (size_t)(m0 + grow) * D_DIM + gc * 8;
  const bf16* bSrc = Bm + (size_t)(n0 + grow) * D_DIM + gc * 8;
  const unsigned wbase = (unsigned)(wv * 1024);     // wave-uniform LDS part

  auto stage_a = [&](int s) {   // A halves of slice s (2 loads)
    const size_t k0 = (size_t)s * 32;
    unsigned as_ = (unsigned)((s & 3) * 16384) + wbase;
    GLOAD_LDS16(aSrc + k0,                          smem + as_);
    GLOAD_LDS16(aSrc + k0 + (size_t)128 * D_DIM,    smem + as_ + 8192);
  };
  auto stage_b = [&](int s) {   // B halves of slice s (2 loads)
    const size_t k0 = (size_t)s * 32;
    unsigned as_ = (unsigned)((s & 3) * 16384) + wbase + 65536;
    GLOAD_LDS16(bSrc + k0,                          smem + as_);
    GLOAD_LDS16(bSrc + k0 + (size_t)128 * D_DIM,    smem + as_ + 8192);
  };

  f32x4 acc[8][4] = {};

  auto body = [&](int s, bool do_stage) {
    SB;                                  // slot s&3 proven (VM before call)
    const char* Ab = smem + (size_t)((s & 3) * 16384);
    const char* Bb = Ab + 65536;
    bf16x8 bf4[4], af[8];
    // ---- cluster 0: reads + A-staging BEFORE the rendezvous barrier ----
#pragma unroll
    for (int j = 0; j < 4; ++j) bf4[j] = *(const bf16x8*)(Bb + baseB + j * 1024);
#pragma unroll
    for (int i = 0; i < 4; ++i) af[i]  = *(const bf16x8*)(Ab + baseA + i * 1024);
    if (do_stage) stage_a(s + 3);
    SCB; SB;
    __builtin_amdgcn_s_setprio(1);
#pragma unroll
    for (int i = 0; i < 4; ++i)
#pragma unroll
      for (int j = 0; j < 4; ++j)
        acc[i][j] = __builtin_amdgcn_mfma_f32_16x16x32_bf16(af[i], bf4[j], acc[i][j], 0, 0, 0);
    __builtin_amdgcn_s_setprio(0);
    SCB;
    // ---- cluster 1: next reads issue while cluster-0 MFMAs drain ----
#pragma unroll
    for (int i = 0; i < 4; ++i) af[4 + i] = *(const bf16x8*)(Ab + baseA + (4 + i) * 1024);
    if (do_stage) stage_b(s + 3);
    SCB; SB;
    __builtin_amdgcn_s_setprio(1);
#pragma unroll
    for (int i = 0; i < 4; ++i)
#pragma unroll
      for (int j = 0; j < 4; ++j)
        acc[4 + i][j] = __builtin_amdgcn_mfma_f32_16x16x32_bf16(af[4 + i], bf4[j], acc[4 + i][j], 0, 0, 0);
    __builtin_amdgcn_s_setprio(0);
    SCB;
  };

  // prologue: slices 0,1,2 in flight (12 loads/thread)
  stage_a(0); stage_b(0);
  stage_a(1); stage_b(1);
  stage_a(2); stage_b(2);

  for (int s = 0; s < 30; ++s) { VM(8); body(s, s < 29); }
  VM(4); body(30, false);
  VM(0); body(31, false);

  // --- epilogue: per-wave LDS transpose, then coalesced float4 stores ---
  // ep region = smem[0..34816) = A-slots 0/1/start-of-2. Slice-31 reads hit
  // slot 3 (A 48K+, B 112K+) — disjoint; slots 0-2's reads all completed
  // before slice-31's start barrier. No extra barrier needed.
  float* ep = (float*)smem + (size_t)wv * (16 * EP_ROWP);  // wave-private

  float bvj[4];
#pragma unroll
  for (int j = 0; j < 4; ++j) bvj[j] = bias[n0 + wn * 64 + j * 16 + lrow];

#pragma unroll
  for (int i = 0; i < 8; ++i) {
#pragma unroll
    for (int j = 0; j < 4; ++j)
#pragma unroll
      for (int r = 0; r < 4; ++r)
        ep[(q * 4 + r) * EP_ROWP + j * 16 + lrow] = acc[i][j][r] + bvj[j];
    // wave-private region: in-wave DS program order suffices, no barrier
#pragma unroll
    for (int it2 = 0; it2 < 4; ++it2) {
      int flat = it2 * 64 + lane;
      int row  = flat >> 4;
      int c16  = flat & 15;
      float4 v = *(const float4*)(ep + row * EP_ROWP + c16 * 4);
      int gm = m0 + wmh * 128 + i * 16 + row;
      int gn = n0 + wn * 64 + c16 * 4;
      *(float4*)(C + (size_t)gm * D_DIM + gn) = v;
    }
  }
}

// ---------------------------------------------------------------------------
// Fallback (only if workspace is too small): correct but slow fp32 path.
// ---------------------------------------------------------------------------
__global__ __launch_bounds__(256) void fallback_kernel(
    const float* __restrict__ x, const float* __restrict__ w_dw,
    const float* __restrict__ b_dw, const float* __restrict__ w_pw,
    const float* __restrict__ b_pw, float* __restrict__ out) {
  __shared__ float ys[D_DIM];
  const int m = blockIdx.x;
  const int l = m & (L_SEQ - 1);
  const int t = threadIdx.x;
  const float* xr = x + (size_t)m * D_DIM;
#pragma unroll
  for (int c = 0; c < 4; ++c) {
    int d = t + c * 256;
    float a = fmaf(xr[d], w_dw[d * 3 + 2], b_dw[d]);
    if (l >= 1) a = fmaf(xr[d - D_DIM], w_dw[d * 3 + 1], a);
    if (l >= 2) a = fmaf(xr[d - 2 * D_DIM], w_dw[d * 3 + 0], a);
    ys[d] = a;
  }
  __syncthreads();
#pragma unroll
  for (int c = 0; c < 4; ++c) {
    int e = t + c * 256;
    const float* wr = w_pw + (size_t)e * D_DIM;
    float a = b_pw[e];
    for (int d = 0; d < D_DIM; ++d) a = fmaf(ys[d], wr[d], a);
    out[(size_t)m * D_DIM + e] = a;
  }
}

extern "C" void kernel_launch(void* const* d_in, const int* in_sizes, int n_in,
                              void* d_out, int out_size, void* d_ws, size_t ws_size,
                              hipStream_t stream) {
  (void)in_sizes; (void)n_in; (void)out_size;
  const float* x    = (const float*)d_in[0];
  const float* w_dw = (const float*)d_in[1];
  const float* b_dw = (const float*)d_in[2];
  const float* w_pw = (const float*)d_in[3];
  const float* b_pw = (const float*)d_in[4];
  float* out = (float*)d_out;

  const size_t y_elems = (size_t)M_TOT * D_DIM;          // 16M bf16 = 32 MB
  const size_t w_elems = (size_t)D_DIM * D_DIM;          // 1M bf16  =  2 MB
  const size_t need = (y_elems + w_elems) * sizeof(bf16);

  if (ws_size >= need) {
    bf16* y    = (bf16*)d_ws;
    bf16* wpwb = (bf16*)d_ws + y_elems;
    const int dw_blocks  = B_SZ * (L_SEQ / 16);          // 1024
    const int cvt_blocks = (D_DIM * D_DIM / 8) / 256;    // 512
    dw_bf16_kernel<<<dw_blocks + cvt_blocks, 256, 0, stream>>>(x, w_dw, b_dw, y, w_pw, wpwb);
    dim3 grid(M_TOT / 256, D_DIM / 256);                 // (64, 4): m fastest
    gemm256_kernel<<<grid, 512, 0, stream>>>(y, wpwb, b_pw, out);
  } else {
    fallback_kernel<<<M_TOT, 256, 0, stream>>>(x, w_dw, b_dw, w_pw, b_pw, out);
  }
}

// Round 6
// 154.135 us; speedup vs baseline: 1.0171x; 1.0171x over previous
//
#include <hip/hip_runtime.h>
#include <hip/hip_bf16.h>
#include <stdint.h>

// Problem constants (B=4, L=4096, D=1024, K=3)
#define B_SZ   4
#define L_SEQ  4096
#define D_DIM  1024
#define M_TOT  (B_SZ * L_SEQ)   // 16384

typedef __bf16 bf16;
typedef __attribute__((ext_vector_type(8))) __bf16 bf16x8;
typedef __attribute__((ext_vector_type(4))) float   f32x4;

#define GLOAD_LDS16(g, l)                                                     \
  __builtin_amdgcn_global_load_lds(                                           \
      (const __attribute__((address_space(1))) void*)(g),                     \
      (__attribute__((address_space(3))) void*)(l), 16, 0, 0)

// ---------------------------------------------------------------------------
// Kernel 1 (VERBATIM, proven): causal depthwise conv (K=3) + bf16 cast.
// Blocks >= M_TOT/16 do w_pw fp32->bf16 (bf16 B keeps the GEMM's B operand
// at 2MB so it stays XCD-L2-resident).
// ---------------------------------------------------------------------------
__global__ __launch_bounds__(256) void dw_bf16_kernel(
    const float* __restrict__ x, const float* __restrict__ w_dw,
    const float* __restrict__ b_dw, bf16* __restrict__ y,
    const float* __restrict__ w_pw, bf16* __restrict__ wpwb) {
  const int t = threadIdx.x;
  if (blockIdx.x >= B_SZ * (L_SEQ / 16)) {
    int i = ((blockIdx.x - B_SZ * (L_SEQ / 16)) * 256 + t) * 8;
    float4 a = *(const float4*)(w_pw + i);
    float4 b = *(const float4*)(w_pw + i + 4);
    union { bf16 h[8]; int4 v; } r;
    r.h[0] = (bf16)a.x; r.h[1] = (bf16)a.y; r.h[2] = (bf16)a.z; r.h[3] = (bf16)a.w;
    r.h[4] = (bf16)b.x; r.h[5] = (bf16)b.y; r.h[6] = (bf16)b.z; r.h[7] = (bf16)b.w;
    *(int4*)(wpwb + i) = r.v;
    return;
  }
  const int b  = blockIdx.x >> 8;     // / (L_SEQ/16 = 256)
  const int l0 = (blockIdx.x & 255) * 16;
  const int d0 = t * 4;
  const float* xb = x + (size_t)b * L_SEQ * D_DIM + d0;
  bf16*        yb = y + (size_t)b * L_SEQ * D_DIM + d0;

  float4 xr[18];
  const float4 zero = make_float4(0.f, 0.f, 0.f, 0.f);
  xr[0] = (l0 >= 2) ? *(const float4*)(xb + (size_t)(l0 - 2) * D_DIM) : zero;
  xr[1] = (l0 >= 1) ? *(const float4*)(xb + (size_t)(l0 - 1) * D_DIM) : zero;
#pragma unroll
  for (int j = 0; j < 16; ++j)
    xr[j + 2] = *(const float4*)(xb + (size_t)(l0 + j) * D_DIM);

  const float* wp = w_dw + d0 * 3;
  float4 wa = *(const float4*)(wp);      // d0:k0,k1,k2  d1:k0
  float4 wb = *(const float4*)(wp + 4);  // d1:k1,k2     d2:k0,k1
  float4 wc = *(const float4*)(wp + 8);  // d2:k2        d3:k0,k1,k2
  float4 bv = *(const float4*)(b_dw + d0);

#pragma unroll
  for (int j = 0; j < 16; ++j) {
    float4 x2 = xr[j], x1 = xr[j + 1], x0 = xr[j + 2];
    float a0 = fmaf(x2.x, wa.x, fmaf(x1.x, wa.y, fmaf(x0.x, wa.z, bv.x)));
    float a1 = fmaf(x2.y, wa.w, fmaf(x1.y, wb.x, fmaf(x0.y, wb.y, bv.y)));
    float a2 = fmaf(x2.z, wb.z, fmaf(x1.z, wb.w, fmaf(x0.z, wc.x, bv.z)));
    float a3 = fmaf(x2.w, wc.y, fmaf(x1.w, wc.z, fmaf(x0.w, wc.w, bv.w)));
    union { bf16 h[4]; int2 v; } o;
    o.h[0] = (bf16)a0; o.h[1] = (bf16)a1; o.h[2] = (bf16)a2; o.h[3] = (bf16)a3;
    *(int2*)(yb + (size_t)(l0 + j) * D_DIM) = o.v;
  }
}

// ---------------------------------------------------------------------------
// Kernel 2: 256x256 GEMM, K-slice ring-4, **16 waves (4 waves/SIMD TLP)**.
//   out[m][n] = sum_k y[m][k] * wpwb[n][k] + b_pw[n]
// M=16384, N=1024, K=1024 -> 32 K-slices of 32.
//
// r4/r5 post-mortem: at 2 waves/SIMD, coarse (r4) and fine (r5) schedules
// both land at 44us -> fixed ~3300cy/slice latency that 2 streams/SIMD can't
// cover. This round holds EVERYTHING else constant (tile, ring slots, VM
// calculus, swizzle, per-CU work per slice) and doubles TLP: 1024 threads,
// 16 waves, wave tile 64x64, acc[4][4] (64 VGPR) -> 4 waves/SIMD (m114's
// implicit wave-level overlap mechanism).
//
// Ring: slice s in slot s&3; A-slots 0..64K, B-slots 64K..128K (16KB each).
// Staging: per slice each THREAD does 1 A-granule + 1 B-granule (1024 thr x
// 16B = 16KB = full slice); per WAVE = 2 DMA instr. VM calculus: prologue
// stages slices 0,1,2 (6/wave outstanding); steady VM(4) retires slice s's 2
// with s+1/s+2 in flight; tail VM(2)/VM(0). Slot-overwrite safety identical
// to r4 (stage(s+3) gated by slice-s barrier; s's reads done before it).
//
// Swizzle (proven r0/r2/r4/r5): read c' = q ^ ((row>>1)&3) at 64B pitch;
// write side pre-swizzles GLOBAL source; LDS dest of gload_lds linear.
// granule g = t: row = t>>2, gc = (t&3) ^ ((row>>1)&3).
//
// GRID (m=x fastest): XCD = bx%8 -> A panel fetched ~once (FETCH 24.6MB).
// ---------------------------------------------------------------------------
#define EP_ROWP 68
#define SB  __builtin_amdgcn_s_barrier()
#define SCB __builtin_amdgcn_sched_barrier(0)
#define VM(N) asm volatile("s_waitcnt vmcnt(" #N ")" ::: "memory")

__global__ __launch_bounds__(1024, 4) void gemm256_kernel(
    const bf16* __restrict__ A,   // M x K row-major (y, bf16)
    const bf16* __restrict__ Bm,  // N x K row-major (wpwb, bf16)
    const float* __restrict__ bias, float* __restrict__ C) {
  __shared__ __align__(16) char smem[131072];
  // A-slots: 0,16K,32K,48K ; B-slots: 64K,80K,96K,112K

  const int t    = threadIdx.x;
  const int m0   = blockIdx.x * 256;  // grid.x = 64 (m) — fastest
  const int n0   = blockIdx.y * 256;  // grid.y = 4 (n)
  const int lane = t & 63;
  const int wv   = t >> 6;    // 0..15
  const int wm4  = wv >> 2;   // 0..3: m-quarter (64 rows)
  const int wn4  = wv & 3;    // 0..3: n-quarter (64 cols)
  const int lrow = lane & 15;
  const int q    = lane >> 4;

  // frag read bases within a slot: row*64 + c'*16, c' = q ^ ((row>>1)&3)
  // (row>>1)&3 == (lrow>>1)&3 for all frags (other row terms mult of 8/16/64)
  const unsigned cx    = (((unsigned)q ^ (((unsigned)lrow >> 1) & 3)) << 4);
  const unsigned baseA = (unsigned)((wm4 * 64 + lrow) * 64) + cx;
  const unsigned baseB = (unsigned)((wn4 * 64 + lrow) * 64) + cx;

  // stage source (pre-swizzled global): granule g = t ->
  // row = t>>2 (0..255), chunk gc = (t&3) ^ ((row>>1)&3)
  const int grow = t >> 2;
  const int gc   = (t & 3) ^ ((grow >> 1) & 3);
  const bf16* aSrc = A  + (size_t)(m0 + grow) * D_DIM + gc * 8;
  const bf16* bSrc = Bm + (size_t)(n0 + grow) * D_DIM + gc * 8;
  const unsigned wbase = (unsigned)(wv * 1024);   // wave-uniform LDS part

  auto stage = [&](int s) {   // 1 A-granule + 1 B-granule per thread
    const size_t k0 = (size_t)s * 32;
    unsigned as_ = (unsigned)((s & 3) * 16384) + wbase;
    GLOAD_LDS16(aSrc + k0, smem + as_);
    GLOAD_LDS16(bSrc + k0, smem + as_ + 65536);
  };

  f32x4 acc[4][4] = {};

  auto body = [&](int s, bool do_stage) {
    SB;                                  // slot s&3 proven (VM before call)
    const char* Ab = smem + (size_t)((s & 3) * 16384);
    const char* Bb = Ab + 65536;
    bf16x8 af[4], bf4[4];
#pragma unroll
    for (int j = 0; j < 4; ++j) bf4[j] = *(const bf16x8*)(Bb + baseB + j * 1024);
#pragma unroll
    for (int i = 0; i < 4; ++i) af[i]  = *(const bf16x8*)(Ab + baseA + i * 1024);
    if (do_stage) stage(s + 3);
    SCB;
    __builtin_amdgcn_s_setprio(1);
#pragma unroll
    for (int i = 0; i < 4; ++i)
#pragma unroll
      for (int j = 0; j < 4; ++j)
        acc[i][j] = __builtin_amdgcn_mfma_f32_16x16x32_bf16(af[i], bf4[j], acc[i][j], 0, 0, 0);
    __builtin_amdgcn_s_setprio(0);
    SCB;
  };

  // prologue: slices 0,1,2 in flight (6 loads/wave)
  stage(0); stage(1); stage(2);

  for (int s = 0; s < 30; ++s) { VM(4); body(s, s <= 28); }
  VM(2); body(30, false);
  VM(0); body(31, false);

  // --- epilogue: per-wave LDS transpose, then coalesced float4 stores ---
  // ep spans smem[0..69632) which overlaps A-slot 3 (48K..64K) and B-slot 0
  // (64K..68K) — slice-31 reads hit A-slot 3, so a full barrier is required
  // before reusing LDS (r4/r5 didn't need it; 16-wave ep region is larger).
  __syncthreads();
  float* ep = (float*)smem + (size_t)wv * (16 * EP_ROWP);  // wave-private 4352B

  float bvj[4];
#pragma unroll
  for (int j = 0; j < 4; ++j) bvj[j] = bias[n0 + wn4 * 64 + j * 16 + lrow];

#pragma unroll
  for (int i = 0; i < 4; ++i) {
#pragma unroll
    for (int j = 0; j < 4; ++j)
#pragma unroll
      for (int r = 0; r < 4; ++r)
        ep[(q * 4 + r) * EP_ROWP + j * 16 + lrow] = acc[i][j][r] + bvj[j];
    // wave-private region: in-wave DS program order suffices, no barrier
#pragma unroll
    for (int it2 = 0; it2 < 4; ++it2) {
      int flat = it2 * 64 + lane;
      int row  = flat >> 4;
      int c16  = flat & 15;
      float4 v = *(const float4*)(ep + row * EP_ROWP + c16 * 4);
      int gm = m0 + wm4 * 64 + i * 16 + row;
      int gn = n0 + wn4 * 64 + c16 * 4;
      *(float4*)(C + (size_t)gm * D_DIM + gn) = v;
    }
  }
}

// ---------------------------------------------------------------------------
// Fallback (only if workspace is too small): correct but slow fp32 path.
// ---------------------------------------------------------------------------
__global__ __launch_bounds__(256) void fallback_kernel(
    const float* __restrict__ x, const float* __restrict__ w_dw,
    const float* __restrict__ b_dw, const float* __restrict__ w_pw,
    const float* __restrict__ b_pw, float* __restrict__ out) {
  __shared__ float ys[D_DIM];
  const int m = blockIdx.x;
  const int l = m & (L_SEQ - 1);
  const int t = threadIdx.x;
  const float* xr = x + (size_t)m * D_DIM;
#pragma unroll
  for (int c = 0; c < 4; ++c) {
    int d = t + c * 256;
    float a = fmaf(xr[d], w_dw[d * 3 + 2], b_dw[d]);
    if (l >= 1) a = fmaf(xr[d - D_DIM], w_dw[d * 3 + 1], a);
    if (l >= 2) a = fmaf(xr[d - 2 * D_DIM], w_dw[d * 3 + 0], a);
    ys[d] = a;
  }
  __syncthreads();
#pragma unroll
  for (int c = 0; c < 4; ++c) {
    int e = t + c * 256;
    const float* wr = w_pw + (size_t)e * D_DIM;
    float a = b_pw[e];
    for (int d = 0; d < D_DIM; ++d) a = fmaf(ys[d], wr[d], a);
    out[(size_t)m * D_DIM + e] = a;
  }
}

extern "C" void kernel_launch(void* const* d_in, const int* in_sizes, int n_in,
                              void* d_out, int out_size, void* d_ws, size_t ws_size,
                              hipStream_t stream) {
  (void)in_sizes; (void)n_in; (void)out_size;
  const float* x    = (const float*)d_in[0];
  const float* w_dw = (const float*)d_in[1];
  const float* b_dw = (const float*)d_in[2];
  const float* w_pw = (const float*)d_in[3];
  const float* b_pw = (const float*)d_in[4];
  float* out = (float*)d_out;

  const size_t y_elems = (size_t)M_TOT * D_DIM;          // 16M bf16 = 32 MB
  const size_t w_elems = (size_t)D_DIM * D_DIM;          // 1M bf16  =  2 MB
  const size_t need = (y_elems + w_elems) * sizeof(bf16);

  if (ws_size >= need) {
    bf16* y    = (bf16*)d_ws;
    bf16* wpwb = (bf16*)d_ws + y_elems;
    const int dw_blocks  = B_SZ * (L_SEQ / 16);          // 1024
    const int cvt_blocks = (D_DIM * D_DIM / 8) / 256;    // 512
    dw_bf16_kernel<<<dw_blocks + cvt_blocks, 256, 0, stream>>>(x, w_dw, b_dw, y, w_pw, wpwb);
    dim3 grid(M_TOT / 256, D_DIM / 256);                 // (64, 4): m fastest
    gemm256_kernel<<<grid, 1024, 0, stream>>>(y, wpwb, b_pw, out);
  } else {
    fallback_kernel<<<M_TOT, 256, 0, stream>>>(x, w_dw, b_dw, w_pw, b_pw, out);
  }
}